// Round 1
// 964.331 us; speedup vs baseline: 1.0381x; 1.0381x over previous
//
#include <hip/hip_runtime.h>
#include <stdint.h>

typedef __bf16 bf16_t;
typedef __bf16 bf16x8 __attribute__((ext_vector_type(8)));
typedef __bf16 bf16x4 __attribute__((ext_vector_type(4)));
typedef float  f32x4  __attribute__((ext_vector_type(4)));

#define MFMA16(a, b, c) __builtin_amdgcn_mfma_f32_16x16x32_bf16((a), (b), (c), 0, 0, 0)

// Async global->LDS 16B/lane. LDS dest is wave-uniform base + lane*16; our
// lds ptr is computed as base + lane*16, matching the HW contract (m97/m104).
__device__ __forceinline__ void load_lds16(const bf16_t* g, bf16_t* l)
{
    __builtin_amdgcn_global_load_lds(
        (const __attribute__((address_space(1))) uint32_t*)(uintptr_t)g,
        (__attribute__((address_space(3))) uint32_t*)(uint32_t)(uintptr_t)l,
        16, 0, 0);
}

// ---------------------------------------------------------------------------
// Weight convert fp32 -> bf16, 8 elems/thread
// ---------------------------------------------------------------------------
__global__ __launch_bounds__(256)
void wconv(const float* __restrict__ X, bf16_t* __restrict__ Y, int n)
{
    int i = (blockIdx.x * 256 + threadIdx.x) * 8;
    if (i >= n) return;
    f32x4 a = *(const f32x4*)(X + i);
    f32x4 b = *(const f32x4*)(X + i + 4);
    bf16x8 y;
#pragma unroll
    for (int e = 0; e < 4; ++e) { y[e] = (bf16_t)a[e]; y[e + 4] = (bf16_t)b[e]; }
    *(bf16x8*)(Y + i) = y;
}

// ---------------------------------------------------------------------------
// RMSNorm (fp32 in -> bf16 out)
// ---------------------------------------------------------------------------
__global__ __launch_bounds__(256)
void rmsnorm_f32(const float* __restrict__ X, const float* __restrict__ Wt,
                 bf16_t* __restrict__ Y)
{
    __shared__ float red[4];
    const int tid = threadIdx.x;
    const size_t row = blockIdx.x;
    const float* x = X + row * 2048;

    f32x4 x0 = *(const f32x4*)(x + tid * 8);
    f32x4 x1 = *(const f32x4*)(x + tid * 8 + 4);
    float ss = 0.f;
#pragma unroll
    for (int e = 0; e < 4; ++e) ss += x0[e] * x0[e] + x1[e] * x1[e];
#pragma unroll
    for (int off = 32; off; off >>= 1) ss += __shfl_xor(ss, off, 64);
    if ((tid & 63) == 0) red[tid >> 6] = ss;
    __syncthreads();
    float tot = red[0] + red[1] + red[2] + red[3];
    float scale = rsqrtf(tot * (1.f / 2048.f) + 1e-6f);

    f32x4 w0 = *(const f32x4*)(Wt + tid * 8);
    f32x4 w1 = *(const f32x4*)(Wt + tid * 8 + 4);
    bf16x8 yv;
#pragma unroll
    for (int e = 0; e < 4; ++e) {
        yv[e]     = (bf16_t)(x0[e] * scale * w0[e]);
        yv[e + 4] = (bf16_t)(x1[e] * scale * w1[e]);
    }
    *(bf16x8*)(Y + row * 2048 + tid * 8) = yv;
}

// ---------------------------------------------------------------------------
// RMSNorm (bf16 in -> bf16 out), fp32 gamma
// ---------------------------------------------------------------------------
__global__ __launch_bounds__(256)
void rmsnorm_bf16(const bf16_t* __restrict__ X, const float* __restrict__ Wt,
                  bf16_t* __restrict__ Y)
{
    __shared__ float red[4];
    const int tid = threadIdx.x;
    const size_t row = blockIdx.x;

    bf16x8 xv = *(const bf16x8*)(X + row * 2048 + tid * 8);
    float xf[8];
    float ss = 0.f;
#pragma unroll
    for (int e = 0; e < 8; ++e) { xf[e] = (float)xv[e]; ss += xf[e] * xf[e]; }
#pragma unroll
    for (int off = 32; off; off >>= 1) ss += __shfl_xor(ss, off, 64);
    if ((tid & 63) == 0) red[tid >> 6] = ss;
    __syncthreads();
    float tot = red[0] + red[1] + red[2] + red[3];
    float scale = rsqrtf(tot * (1.f / 2048.f) + 1e-6f);

    f32x4 w0 = *(const f32x4*)(Wt + tid * 8);
    f32x4 w1 = *(const f32x4*)(Wt + tid * 8 + 4);
    bf16x8 yv;
#pragma unroll
    for (int e = 0; e < 4; ++e) {
        yv[e]     = (bf16_t)(xf[e] * scale * w0[e]);
        yv[e + 4] = (bf16_t)(xf[e + 4] * scale * w1[e]);
    }
    *(bf16x8*)(Y + row * 2048 + tid * 8) = yv;
}

// ---------------------------------------------------------------------------
// FAST PATH GEMM (pure bf16, global_load_lds staging, m97 structure):
// C[M,N] = A[M,K] @ W[N,K]^T, fp32 acc.
// mode 0: Cb = acc | mode 1: Cb = acc + Rf(fp32) | mode 2: Cf = acc + Rb(bf16)
// ---------------------------------------------------------------------------
__global__ __launch_bounds__(256, 2)
void gemm_bb(const bf16_t* __restrict__ A, const bf16_t* __restrict__ W,
             const float* __restrict__ Rf, const bf16_t* __restrict__ Rb,
             bf16_t* __restrict__ Cb, float* __restrict__ Cf,
             int M, int N, int K, int mode)
{
    __shared__ bf16_t As[128 * 64];
    __shared__ bf16_t Ws[128 * 64];

    const int tid  = threadIdx.x;
    const int lane = tid & 63, wave = tid >> 6;
    const int quad = lane >> 4, l16 = lane & 15;
    const int m0 = blockIdx.y * 128, n0 = blockIdx.x * 128;
    const int wm = (wave >> 1) * 64, wn = (wave & 1) * 64;

    const bf16_t* Ab = A + (size_t)(m0 + (tid >> 3)) * K + ((tid & 7) << 3);
    const bf16_t* Wb = W + (size_t)(n0 + (tid >> 3)) * K + ((tid & 7) << 3);

    f32x4 acc[4][4] = {};

    for (int k0 = 0; k0 < K; k0 += 64) {
        __syncthreads();
#pragma unroll
        for (int i = 0; i < 4; ++i) {
            load_lds16(Ab + (size_t)(i * 32) * K + k0, As + (i * 256 + tid) * 8);
            load_lds16(Wb + (size_t)(i * 32) * K + k0, Ws + (i * 256 + tid) * 8);
        }
        __syncthreads();

#pragma unroll
        for (int ks = 0; ks < 64; ks += 32) {
            bf16x8 af[4], bfr[4];
#pragma unroll
            for (int i = 0; i < 4; ++i)
                af[i] = *(const bf16x8*)(As + (wm + i * 16 + l16) * 64 + ks + quad * 8);
#pragma unroll
            for (int j = 0; j < 4; ++j)
                bfr[j] = *(const bf16x8*)(Ws + (wn + j * 16 + l16) * 64 + ks + quad * 8);
#pragma unroll
            for (int i = 0; i < 4; ++i)
#pragma unroll
                for (int j = 0; j < 4; ++j)
                    acc[i][j] = MFMA16(af[i], bfr[j], acc[i][j]);
        }
    }

#pragma unroll
    for (int i = 0; i < 4; ++i)
#pragma unroll
        for (int j = 0; j < 4; ++j)
#pragma unroll
            for (int r = 0; r < 4; ++r) {
                size_t row = (size_t)(m0 + wm + i * 16 + quad * 4 + r);
                size_t col = (size_t)(n0 + wn + j * 16 + l16);
                float v = acc[i][j][r];
                if (mode == 1) v += Rf[row * (size_t)N + col];
                if (mode == 2)
                    Cf[row * (size_t)N + col] = v + (float)Rb[row * (size_t)N + col];
                else
                    Cb[row * (size_t)N + col] = (bf16_t)v;
            }
}

// ---------------------------------------------------------------------------
// NEW: fused gate+up SwiGLU GEMM, phase-split 256x128 tile, 8 waves,
// double-buffered LDS (128 KiB), counted vmcnt(8) (T3+T4), XOR-swizzled LDS
// (T2, via pre-swizzled global source for linear global_load_lds dest),
// setprio around MFMA clusters (T5), bijective XCD block swizzle (T1).
//
// C[M,N] = silu(A@G^T) * (A@U^T);  A[M,K], G/U[N,K] bf16, fp32 acc.
// Grid: 1-D M/256 * N/128 blocks of 512 threads.
// ---------------------------------------------------------------------------
__device__ __forceinline__ void stage_gu(const bf16_t* __restrict__ Ab,
                                         const bf16_t* __restrict__ Gb,
                                         const bf16_t* __restrict__ Ub,
                                         bf16_t* As, bf16_t* Gs, bf16_t* Us,
                                         int tid, int K, int k0)
{
    // 8 global_load_lds per thread (wave-order: A x4, then G,U,G,U).
    // Linear LDS dest u*16B; source col pre-XORed so that a reader applying
    // elem_off ^= (row&7)<<3 sees the logical layout (involution, rule 21).
#pragma unroll
    for (int l = 0; l < 4; ++l) {
        int u = l * 512 + tid;
        int row = u >> 3;
        int col = (((u & 7) ^ (row & 7)) << 3);
        load_lds16(Ab + (size_t)row * K + k0 + col, As + u * 8);
    }
#pragma unroll
    for (int l = 0; l < 2; ++l) {
        int u = l * 512 + tid;
        int row = u >> 3;
        int col = (((u & 7) ^ (row & 7)) << 3);
        load_lds16(Gb + (size_t)row * K + k0 + col, Gs + u * 8);
        load_lds16(Ub + (size_t)row * K + k0 + col, Us + u * 8);
    }
}

__global__ __launch_bounds__(512, 2)
void gateup8(const bf16_t* __restrict__ A, const bf16_t* __restrict__ G,
             const bf16_t* __restrict__ U, bf16_t* __restrict__ C,
             int M, int N, int K)
{
    __shared__ bf16_t As[2][256 * 64];   // 64 KiB
    __shared__ bf16_t Gs[2][128 * 64];   // 32 KiB
    __shared__ bf16_t Us[2][128 * 64];   // 32 KiB

    const int tid  = threadIdx.x;
    const int lane = tid & 63;
    const int wave = tid >> 6;
    const int quad = lane >> 4, l16 = lane & 15;
    const int wr = wave >> 2, wc = wave & 3;      // 2M x 4N wave grid

    // T1: bijective XCD swizzle (704 blocks, 704 % 8 == 0). Col-major tile id
    // so each XCD keeps ~5 G/U column-panels L2-resident while A streams L3.
    const int lid = (int)blockIdx.x;
    const int nwg = (M >> 8) * (N >> 7);          // 16 * 44 = 704
    const int cpx = nwg >> 3;                     // 88
    const int swz = (lid & 7) * cpx + (lid >> 3);
    const int bxn = swz >> 4;                     // N-block (44)
    const int bym = swz & 15;                     // M-block (16)
    const int m0 = bym * 256, n0 = bxn * 128;

    const bf16_t* Ab = A + (size_t)m0 * K;
    const bf16_t* Gb = G + (size_t)n0 * K;
    const bf16_t* Ub = U + (size_t)n0 * K;

    const int xsw  = (l16 & 7) << 3;              // T2 read-side XOR (elems)
    const int aoff = (wr * 128 + l16) * 64;
    const int boff = (wc * 32 + l16) * 64;

    f32x4 accg[8][2] = {};
    f32x4 accu[8][2] = {};

    stage_gu(Ab, Gb, Ub, As[0], Gs[0], Us[0], tid, K, 0);

    const int NT = K >> 6;                        // 32 K-tiles
    for (int t = 0; t < NT; ++t) {
        const int b = t & 1;
        if (t + 1 < NT) {
            // burst-prefetch next K-tile into the other buffer; its reads-of-
            // record finished at the end barrier of iter t-1 (race-free).
            stage_gu(Ab, Gb, Ub, As[1 - b], Gs[1 - b], Us[1 - b],
                     tid, K, (t + 1) << 6);
            // T4: drain exactly THIS tile's 8 loads; next tile's 8 stay in
            // flight across all barriers below (never vmcnt(0) mid-loop).
            asm volatile("s_waitcnt vmcnt(8)" ::: "memory");
        } else {
            asm volatile("s_waitcnt vmcnt(0)" ::: "memory");
        }
        __builtin_amdgcn_s_barrier();   // all waves' stage of tile t landed

        const bf16_t* Asb = As[b];
        const bf16_t* Gsb = Gs[b];
        const bf16_t* Usb = Us[b];

#pragma unroll
        for (int ks = 0; ks < 64; ks += 32) {
            const int kxo = (ks + quad * 8) ^ xsw;
            bf16x8 af[8], bb[2];
            // ---- phase: G, this ks-half (8 + 2 ds_read_b128) ----
#pragma unroll
            for (int i = 0; i < 8; ++i)
                af[i] = *(const bf16x8*)(Asb + aoff + i * 1024 + kxo);
#pragma unroll
            for (int j = 0; j < 2; ++j)
                bb[j] = *(const bf16x8*)(Gsb + boff + j * 1024 + kxo);
            __builtin_amdgcn_s_barrier();
            __builtin_amdgcn_s_setprio(1);
#pragma unroll
            for (int i = 0; i < 8; ++i)
#pragma unroll
                for (int j = 0; j < 2; ++j)
                    accg[i][j] = MFMA16(af[i], bb[j], accg[i][j]);
            __builtin_amdgcn_s_setprio(0);
            __builtin_amdgcn_s_barrier();
            // ---- phase: U, same ks-half (2 ds_read_b128, reuse af) ----
#pragma unroll
            for (int j = 0; j < 2; ++j)
                bb[j] = *(const bf16x8*)(Usb + boff + j * 1024 + kxo);
            __builtin_amdgcn_s_barrier();
            __builtin_amdgcn_s_setprio(1);
#pragma unroll
            for (int i = 0; i < 8; ++i)
#pragma unroll
                for (int j = 0; j < 2; ++j)
                    accu[i][j] = MFMA16(af[i], bb[j], accu[i][j]);
            __builtin_amdgcn_s_setprio(0);
            __builtin_amdgcn_s_barrier();   // last one doubles as end-of-tile
        }
    }

    // epilogue: silu(g) * u
#pragma unroll
    for (int i = 0; i < 8; ++i)
#pragma unroll
        for (int j = 0; j < 2; ++j)
#pragma unroll
            for (int r = 0; r < 4; ++r) {
                size_t row = (size_t)(m0 + wr * 128 + i * 16 + quad * 4 + r);
                size_t col = (size_t)(n0 + wc * 32 + j * 16 + l16);
                float g = accg[i][j][r];
                float u = accu[i][j][r];
                float sig = 1.f / (1.f + __expf(fminf(-g, 80.f)));
                C[row * (size_t)N + col] = (bf16_t)(g * sig * u);
            }
}

// ---------------------------------------------------------------------------
// FALLBACK GEMM (round-4 path, fp32 weights staged in registers)
// ---------------------------------------------------------------------------
__global__ __launch_bounds__(256, 2)
void gemm_bt(const bf16_t* __restrict__ A, const float* __restrict__ W,
             const float* __restrict__ Rf, const bf16_t* __restrict__ Rb,
             bf16_t* __restrict__ Cb, float* __restrict__ Cf,
             int M, int N, int K, int mode)
{
    __shared__ bf16_t As[128 * 64];
    __shared__ bf16_t Ws[128 * 64];

    const int tid  = threadIdx.x;
    const int lane = tid & 63, wave = tid >> 6;
    const int quad = lane >> 4, l16 = lane & 15;
    const int m0 = blockIdx.y * 128, n0 = blockIdx.x * 128;
    const int wm = (wave >> 1) * 64, wn = (wave & 1) * 64;

    f32x4 acc[4][4] = {};

    for (int k0 = 0; k0 < K; k0 += 64) {
        bf16x8 ra[4];
        bf16x4 rw[8];
#pragma unroll
        for (int i = 0; i < 4; ++i) {
            int u = i * 256 + tid;
            int r = u >> 3, c = (u & 7) << 3;
            ra[i] = *(const bf16x8*)(A + (size_t)(m0 + r) * K + k0 + c);
        }
#pragma unroll
        for (int i = 0; i < 8; ++i) {
            int u = i * 256 + tid;
            int r = u >> 4, c = (u & 15) << 2;
            f32x4 w4 = *(const f32x4*)(W + (size_t)(n0 + r) * K + k0 + c);
#pragma unroll
            for (int e = 0; e < 4; ++e) rw[i][e] = (bf16_t)w4[e];
        }
        __syncthreads();
#pragma unroll
        for (int i = 0; i < 4; ++i)
            *(bf16x8*)(As + (i * 256 + tid) * 8) = ra[i];
#pragma unroll
        for (int i = 0; i < 8; ++i)
            *(bf16x4*)(Ws + (i * 256 + tid) * 4) = rw[i];
        __syncthreads();

#pragma unroll
        for (int ks = 0; ks < 64; ks += 32) {
            bf16x8 af[4], bfr[4];
#pragma unroll
            for (int i = 0; i < 4; ++i)
                af[i] = *(const bf16x8*)(As + (wm + i * 16 + l16) * 64 + ks + quad * 8);
#pragma unroll
            for (int j = 0; j < 4; ++j)
                bfr[j] = *(const bf16x8*)(Ws + (wn + j * 16 + l16) * 64 + ks + quad * 8);
#pragma unroll
            for (int i = 0; i < 4; ++i)
#pragma unroll
                for (int j = 0; j < 4; ++j)
                    acc[i][j] = MFMA16(af[i], bfr[j], acc[i][j]);
        }
    }

#pragma unroll
    for (int i = 0; i < 4; ++i)
#pragma unroll
        for (int j = 0; j < 4; ++j)
#pragma unroll
            for (int r = 0; r < 4; ++r) {
                size_t row = (size_t)(m0 + wm + i * 16 + quad * 4 + r);
                size_t col = (size_t)(n0 + wn + j * 16 + l16);
                float v = acc[i][j][r];
                if (mode == 1) v += Rf[row * (size_t)N + col];
                if (mode == 2)
                    Cf[row * (size_t)N + col] = v + (float)Rb[row * (size_t)N + col];
                else
                    Cb[row * (size_t)N + col] = (bf16_t)v;
            }
}

// ---------------------------------------------------------------------------
// FALLBACK fused gate+up (round-4 path, fp32 weights)
// ---------------------------------------------------------------------------
__global__ __launch_bounds__(256, 2)
void gemm_gateup(const bf16_t* __restrict__ A, const float* __restrict__ G,
                 const float* __restrict__ U, bf16_t* __restrict__ C,
                 int M, int N, int K)
{
    __shared__ bf16_t As[128 * 64];
    __shared__ bf16_t Gs[128 * 64];
    __shared__ bf16_t Us[128 * 64];

    const int tid  = threadIdx.x;
    const int lane = tid & 63, wave = tid >> 6;
    const int quad = lane >> 4, l16 = lane & 15;
    const int m0 = blockIdx.y * 128, n0 = blockIdx.x * 128;
    const int wm = (wave >> 1) * 64, wn = (wave & 1) * 64;

    f32x4 accg[4][4] = {};
    f32x4 accu[4][4] = {};

    for (int k0 = 0; k0 < K; k0 += 64) {
        bf16x8 ra[4];
        bf16x4 rg[8], ru[8];
#pragma unroll
        for (int i = 0; i < 4; ++i) {
            int u = i * 256 + tid;
            int r = u >> 3, c = (u & 7) << 3;
            ra[i] = *(const bf16x8*)(A + (size_t)(m0 + r) * K + k0 + c);
        }
#pragma unroll
        for (int i = 0; i < 8; ++i) {
            int u = i * 256 + tid;
            int r = u >> 4, c = (u & 15) << 2;
            f32x4 g4 = *(const f32x4*)(G + (size_t)(n0 + r) * K + k0 + c);
            f32x4 u4 = *(const f32x4*)(U + (size_t)(n0 + r) * K + k0 + c);
#pragma unroll
            for (int e = 0; e < 4; ++e) { rg[i][e] = (bf16_t)g4[e]; ru[i][e] = (bf16_t)u4[e]; }
        }
        __syncthreads();
#pragma unroll
        for (int i = 0; i < 4; ++i)
            *(bf16x8*)(As + (i * 256 + tid) * 8) = ra[i];
#pragma unroll
        for (int i = 0; i < 8; ++i) {
            *(bf16x4*)(Gs + (i * 256 + tid) * 4) = rg[i];
            *(bf16x4*)(Us + (i * 256 + tid) * 4) = ru[i];
        }
        __syncthreads();

#pragma unroll
        for (int ks = 0; ks < 64; ks += 32) {
            bf16x8 af[4], bg[4], bu[4];
#pragma unroll
            for (int i = 0; i < 4; ++i)
                af[i] = *(const bf16x8*)(As + (wm + i * 16 + l16) * 64 + ks + quad * 8);
#pragma unroll
            for (int j = 0; j < 4; ++j) {
                bg[j] = *(const bf16x8*)(Gs + (wn + j * 16 + l16) * 64 + ks + quad * 8);
                bu[j] = *(const bf16x8*)(Us + (wn + j * 16 + l16) * 64 + ks + quad * 8);
            }
#pragma unroll
            for (int i = 0; i < 4; ++i)
#pragma unroll
                for (int j = 0; j < 4; ++j) {
                    accg[i][j] = MFMA16(af[i], bg[j], accg[i][j]);
                    accu[i][j] = MFMA16(af[i], bu[j], accu[i][j]);
                }
        }
    }

#pragma unroll
    for (int i = 0; i < 4; ++i)
#pragma unroll
        for (int j = 0; j < 4; ++j)
#pragma unroll
            for (int r = 0; r < 4; ++r) {
                size_t row = (size_t)(m0 + wm + i * 16 + quad * 4 + r);
                size_t col = (size_t)(n0 + wn + j * 16 + l16);
                float g = accg[i][j][r];
                float u = accu[i][j][r];
                float sig = 1.f / (1.f + __expf(fminf(-g, 80.f)));
                C[row * (size_t)N + col] = (bf16_t)(g * sig * u);
            }
}

// ---------------------------------------------------------------------------
// Flash attention fwd (round-4 version: swizzled Vt, padded Pl, paired q-tiles)
// ---------------------------------------------------------------------------
__global__ __launch_bounds__(256, 2)
void attn_fwd(const bf16_t* __restrict__ Q, const bf16_t* __restrict__ Kg,
              const bf16_t* __restrict__ Vg, bf16_t* __restrict__ O)
{
    __shared__ bf16_t Ks[64 * 128];
    __shared__ bf16_t Vt[128 * 64];      // Vt[d][k], k-blocks XOR-swizzled by d&7
    __shared__ bf16_t Pl[4][16 * 72];    // padded stride 72

    const int tid  = threadIdx.x;
    const int lane = tid & 63, wave = tid >> 6;
    const int quad = lane >> 4, l16 = lane & 15;
    const int bh = blockIdx.y, b = bh >> 4, h = bh & 15;

    const bf16_t* Qh = Q  + (size_t)b * 2048 * 2048 + (size_t)h * 128;
    const bf16_t* Kh = Kg + (size_t)b * 2048 * 1024 + (size_t)(h >> 1) * 128;
    const bf16_t* Vh = Vg + (size_t)b * 2048 * 1024 + (size_t)(h >> 1) * 128;

    const float scale = 0.08838834764831845f;   // 1/sqrt(128)

#pragma unroll 1
    for (int pass = 0; pass < 2; ++pass) {
        const int qt = pass ? (31 - (int)blockIdx.x) : (int)blockIdx.x;
        const int q0 = qt * 64;

        bf16x8 aq[4];
#pragma unroll
        for (int ks = 0; ks < 4; ++ks)
            aq[ks] = *(const bf16x8*)(Qh + (size_t)(q0 + wave * 16 + l16) * 2048 + ks * 32 + quad * 8);

        float m_r[4] = { -30000.f, -30000.f, -30000.f, -30000.f };
        float l_r[4] = { 0.f, 0.f, 0.f, 0.f };
        f32x4 acc_o[8] = {};

        const int ntiles = qt + 1;

        for (int t = 0; t < ntiles; ++t) {
            const int kv0 = t * 64;
            __syncthreads();
#pragma unroll
            for (int i = 0; i < 4; ++i) {
                int u = i * 256 + tid;
                int rk = u >> 4, c = (u & 15) << 3;
                *(bf16x8*)(Ks + u * 8) =
                    *(const bf16x8*)(Kh + (size_t)(kv0 + rk) * 1024 + c);
            }
#pragma unroll
            for (int it = 0; it < 4; ++it) {
                int v = it * 256 + tid;
                int d = v & 127, kb = v >> 7;
                bf16x8 vt8;
#pragma unroll
                for (int j = 0; j < 8; ++j)
                    vt8[j] = Vh[(size_t)(kv0 + kb * 8 + j) * 1024 + d];
                *(bf16x8*)(Vt + d * 64 + ((kb ^ (d & 7)) << 3)) = vt8;
            }
            __syncthreads();

            f32x4 accs[4] = {};
#pragma unroll
            for (int ks = 0; ks < 4; ++ks)
#pragma unroll
                for (int j = 0; j < 4; ++j) {
                    bf16x8 bk = *(const bf16x8*)(Ks + (j * 16 + l16) * 128 + ks * 32 + quad * 8);
                    accs[j] = MFMA16(aq[ks], bk, accs[j]);
                }

#pragma unroll
            for (int r = 0; r < 4; ++r) {
                const int qrow = q0 + wave * 16 + quad * 4 + r;
                float s[4];
                float mx = -30000.f;
#pragma unroll
                for (int j = 0; j < 4; ++j) {
                    s[j] = accs[j][r] * scale;
                    if (kv0 + j * 16 + l16 > qrow) s[j] = -30000.f;
                    mx = fmaxf(mx, s[j]);
                }
                mx = fmaxf(mx, __shfl_xor(mx, 1, 64));
                mx = fmaxf(mx, __shfl_xor(mx, 2, 64));
                mx = fmaxf(mx, __shfl_xor(mx, 4, 64));
                mx = fmaxf(mx, __shfl_xor(mx, 8, 64));
                float mnew  = fmaxf(m_r[r], mx);
                float alpha = __expf(fmaxf(m_r[r] - mnew, -80.f));
                float rs = 0.f;
#pragma unroll
                for (int j = 0; j < 4; ++j) {
                    float p = __expf(fmaxf(s[j] - mnew, -80.f));
                    rs += p;
                    Pl[wave][(quad * 4 + r) * 72 + j * 16 + l16] = (bf16_t)p;
                }
                rs += __shfl_xor(rs, 1, 64);
                rs += __shfl_xor(rs, 2, 64);
                rs += __shfl_xor(rs, 4, 64);
                rs += __shfl_xor(rs, 8, 64);
                l_r[r] = l_r[r] * alpha + rs;
                m_r[r] = mnew;
#pragma unroll
                for (int nt = 0; nt < 8; ++nt) acc_o[nt][r] *= alpha;
            }

            __syncthreads();

#pragma unroll
            for (int ks2 = 0; ks2 < 2; ++ks2) {
                bf16x8 ap = *(const bf16x8*)(&Pl[wave][l16 * 72 + ks2 * 32 + quad * 8]);
                const int kb_r = ks2 * 4 + quad;
#pragma unroll
                for (int nt = 0; nt < 8; ++nt) {
                    const int d = nt * 16 + l16;
                    bf16x8 bv = *(const bf16x8*)(Vt + d * 64 + ((kb_r ^ (d & 7)) << 3));
                    acc_o[nt] = MFMA16(ap, bv, acc_o[nt]);
                }
            }
        }

#pragma unroll
        for (int r = 0; r < 4; ++r) {
            float inv = 1.f / fmaxf(l_r[r], 1e-30f);
            size_t orow = (size_t)b * 2048 + q0 + wave * 16 + quad * 4 + r;
#pragma unroll
            for (int nt = 0; nt < 8; ++nt)
                O[orow * 2048 + h * 128 + nt * 16 + l16] = (bf16_t)(acc_o[nt][r] * inv);
        }
    }
}

// ---------------------------------------------------------------------------
// Launch. Fast path (ws >= 174 MB): pre-convert weights to bf16 once, then
// pure-bf16 GEMMs with global_load_lds. Fallback: round-4 mixed path.
// Branch is on ws_size (constant across calls) -> graph-capture safe.
// ---------------------------------------------------------------------------
extern "C" void kernel_launch(void* const* d_in, const int* in_sizes, int n_in,
                              void* d_out, int out_size, void* d_ws, size_t ws_size,
                              hipStream_t stream)
{
    const float* x   = (const float*)d_in[0];
    const float* qw  = (const float*)d_in[2];
    const float* kw  = (const float*)d_in[3];
    const float* vw  = (const float*)d_in[4];
    const float* ow  = (const float*)d_in[5];
    const float* gw  = (const float*)d_in[6];
    const float* uw  = (const float*)d_in[7];
    const float* dw  = (const float*)d_in[8];
    const float* ln1 = (const float*)d_in[9];
    const float* ln2 = (const float*)d_in[10];
    float*  out = (float*)d_out;
    bf16_t* ws  = (bf16_t*)d_ws;

    dim3 blk(256);
    const size_t NEED = 87031808ull * 2;   // 174 MB

    if (ws_size >= NEED) {
        // ---- fast path: bf16 weights + global_load_lds GEMMs ----
        bf16_t* wq = ws;                      // 4,194,304
        bf16_t* wk = ws + 4194304;            // 2,097,152
        bf16_t* wv = ws + 6291456;            // 2,097,152
        bf16_t* wo = ws + 8388608;            // 4,194,304
        bf16_t* wg = ws + 12582912;           // 11,534,336
        bf16_t* wu = ws + 24117248;           // 11,534,336
        bf16_t* wd = ws + 35651584;           // 11,534,336
        bf16_t* h1 = ws + 47185920;           // 8,388,608
        bf16_t* qb = ws + 55574528;           // 8,388,608 (later hb)
        bf16_t* kb = ws + 63963136;           // 4,194,304 (later gb)
        bf16_t* vb = ws + 68157440;           // 4,194,304
        bf16_t* ab = (bf16_t*)d_out;          // attn out scratch in d_out
        bf16_t* hb = qb;
        bf16_t* gb = kb;                      // 23,068,672 ends at 87,031,808

        wconv<<<2048, blk, 0, stream>>>(qw, wq, 4194304);
        wconv<<<1024, blk, 0, stream>>>(kw, wk, 2097152);
        wconv<<<1024, blk, 0, stream>>>(vw, wv, 2097152);
        wconv<<<2048, blk, 0, stream>>>(ow, wo, 4194304);
        wconv<<<5632, blk, 0, stream>>>(gw, wg, 11534336);
        wconv<<<5632, blk, 0, stream>>>(uw, wu, 11534336);
        wconv<<<5632, blk, 0, stream>>>(dw, wd, 11534336);

        rmsnorm_f32<<<4096, blk, 0, stream>>>(x, ln1, h1);
        gemm_bb<<<dim3(16, 32), blk, 0, stream>>>(h1, wq, nullptr, nullptr, qb, nullptr, 4096, 2048, 2048, 0);
        gemm_bb<<<dim3( 8, 32), blk, 0, stream>>>(h1, wk, nullptr, nullptr, kb, nullptr, 4096, 1024, 2048, 0);
        gemm_bb<<<dim3( 8, 32), blk, 0, stream>>>(h1, wv, nullptr, nullptr, vb, nullptr, 4096, 1024, 2048, 0);
        attn_fwd<<<dim3(16, 32), blk, 0, stream>>>(qb, kb, vb, ab);
        gemm_bb<<<dim3(16, 32), blk, 0, stream>>>(ab, wo, x, nullptr, hb, nullptr, 4096, 2048, 2048, 1);
        rmsnorm_bf16<<<4096, blk, 0, stream>>>(hb, ln2, h1);
        gateup8<<<704, dim3(512), 0, stream>>>(h1, wg, wu, gb, 4096, 5632, 2048);
        gemm_bb<<<dim3(16, 32), blk, 0, stream>>>(gb, wd, nullptr, hb, nullptr, out, 4096, 2048, 5632, 2);
    } else {
        // ---- fallback: round-4 mixed path (78 MB) ----
        const size_t ME = 1ull << 20;
        bf16_t* h1 = ws;
        bf16_t* qb = ws + 8  * ME;
        bf16_t* kb = ws + 16 * ME;
        bf16_t* vb = ws + 20 * ME;
        bf16_t* ab = (bf16_t*)d_out;
        bf16_t* hb = ws + 8  * ME;
        bf16_t* gb = ws + 16 * ME;

        rmsnorm_f32<<<4096, blk, 0, stream>>>(x, ln1, h1);
        gemm_bt<<<dim3(16, 32), blk, 0, stream>>>(h1, qw, nullptr, nullptr, qb, nullptr, 4096, 2048, 2048, 0);
        gemm_bt<<<dim3( 8, 32), blk, 0, stream>>>(h1, kw, nullptr, nullptr, kb, nullptr, 4096, 1024, 2048, 0);
        gemm_bt<<<dim3( 8, 32), blk, 0, stream>>>(h1, vw, nullptr, nullptr, vb, nullptr, 4096, 1024, 2048, 0);
        attn_fwd<<<dim3(16, 32), blk, 0, stream>>>(qb, kb, vb, ab);
        gemm_bt<<<dim3(16, 32), blk, 0, stream>>>(ab, ow, x, nullptr, hb, nullptr, 4096, 2048, 2048, 1);
        rmsnorm_bf16<<<4096, blk, 0, stream>>>(hb, ln2, h1);
        gemm_gateup<<<dim3(44, 32), blk, 0, stream>>>(h1, gw, uw, gb, 4096, 5632, 2048);
        gemm_bt<<<dim3(16, 32), blk, 0, stream>>>(gb, dw, nullptr, hb, nullptr, out, 4096, 2048, 5632, 2);
    }
}

// Round 2
// 887.223 us; speedup vs baseline: 1.1284x; 1.0869x over previous
//
#include <hip/hip_runtime.h>
#include <stdint.h>

typedef __bf16 bf16_t;
typedef __bf16 bf16x8 __attribute__((ext_vector_type(8)));
typedef __bf16 bf16x4 __attribute__((ext_vector_type(4)));
typedef float  f32x4  __attribute__((ext_vector_type(4)));

#define MFMA16(a, b, c) __builtin_amdgcn_mfma_f32_16x16x32_bf16((a), (b), (c), 0, 0, 0)

// Async global->LDS 16B/lane. LDS dest is wave-uniform base + lane*16; our
// lds ptr is computed as base + lane*16, matching the HW contract (m97/m104).
__device__ __forceinline__ void load_lds16(const bf16_t* g, bf16_t* l)
{
    __builtin_amdgcn_global_load_lds(
        (const __attribute__((address_space(1))) uint32_t*)(uintptr_t)g,
        (__attribute__((address_space(3))) uint32_t*)(uint32_t)(uintptr_t)l,
        16, 0, 0);
}

// Stage 2x16B per thread into LDS with T2 inverse-swizzled global source.
// LDS linear slot u*16B holds global[row][ (x ^ ((row&7)<<3)) ] for x in the
// 8-elem group; readers apply the same XOR (involution, rule 21).
__device__ __forceinline__ void lds_stage2(const bf16_t* __restrict__ Gsrc,
                                           bf16_t* Ldst, int u0,
                                           int tid, int K, int k0)
{
#pragma unroll
    for (int l = 0; l < 2; ++l) {
        int u = u0 + l * 512 + tid;
        int row = u >> 3;
        int col = (((u & 7) ^ (row & 7)) << 3);
        load_lds16(Gsrc + (size_t)row * K + k0 + col, Ldst + u * 8);
    }
}

// ---------------------------------------------------------------------------
// Weight convert fp32 -> bf16, 8 elems/thread
// ---------------------------------------------------------------------------
__global__ __launch_bounds__(256)
void wconv(const float* __restrict__ X, bf16_t* __restrict__ Y, int n)
{
    int i = (blockIdx.x * 256 + threadIdx.x) * 8;
    if (i >= n) return;
    f32x4 a = *(const f32x4*)(X + i);
    f32x4 b = *(const f32x4*)(X + i + 4);
    bf16x8 y;
#pragma unroll
    for (int e = 0; e < 4; ++e) { y[e] = (bf16_t)a[e]; y[e + 4] = (bf16_t)b[e]; }
    *(bf16x8*)(Y + i) = y;
}

// ---------------------------------------------------------------------------
// RMSNorm (fp32 in -> bf16 out)
// ---------------------------------------------------------------------------
__global__ __launch_bounds__(256)
void rmsnorm_f32(const float* __restrict__ X, const float* __restrict__ Wt,
                 bf16_t* __restrict__ Y)
{
    __shared__ float red[4];
    const int tid = threadIdx.x;
    const size_t row = blockIdx.x;
    const float* x = X + row * 2048;

    f32x4 x0 = *(const f32x4*)(x + tid * 8);
    f32x4 x1 = *(const f32x4*)(x + tid * 8 + 4);
    float ss = 0.f;
#pragma unroll
    for (int e = 0; e < 4; ++e) ss += x0[e] * x0[e] + x1[e] * x1[e];
#pragma unroll
    for (int off = 32; off; off >>= 1) ss += __shfl_xor(ss, off, 64);
    if ((tid & 63) == 0) red[tid >> 6] = ss;
    __syncthreads();
    float tot = red[0] + red[1] + red[2] + red[3];
    float scale = rsqrtf(tot * (1.f / 2048.f) + 1e-6f);

    f32x4 w0 = *(const f32x4*)(Wt + tid * 8);
    f32x4 w1 = *(const f32x4*)(Wt + tid * 8 + 4);
    bf16x8 yv;
#pragma unroll
    for (int e = 0; e < 4; ++e) {
        yv[e]     = (bf16_t)(x0[e] * scale * w0[e]);
        yv[e + 4] = (bf16_t)(x1[e] * scale * w1[e]);
    }
    *(bf16x8*)(Y + row * 2048 + tid * 8) = yv;
}

// ---------------------------------------------------------------------------
// RMSNorm (bf16 in -> bf16 out), fp32 gamma
// ---------------------------------------------------------------------------
__global__ __launch_bounds__(256)
void rmsnorm_bf16(const bf16_t* __restrict__ X, const float* __restrict__ Wt,
                  bf16_t* __restrict__ Y)
{
    __shared__ float red[4];
    const int tid = threadIdx.x;
    const size_t row = blockIdx.x;

    bf16x8 xv = *(const bf16x8*)(X + row * 2048 + tid * 8);
    float xf[8];
    float ss = 0.f;
#pragma unroll
    for (int e = 0; e < 8; ++e) { xf[e] = (float)xv[e]; ss += xf[e] * xf[e]; }
#pragma unroll
    for (int off = 32; off; off >>= 1) ss += __shfl_xor(ss, off, 64);
    if ((tid & 63) == 0) red[tid >> 6] = ss;
    __syncthreads();
    float tot = red[0] + red[1] + red[2] + red[3];
    float scale = rsqrtf(tot * (1.f / 2048.f) + 1e-6f);

    f32x4 w0 = *(const f32x4*)(Wt + tid * 8);
    f32x4 w1 = *(const f32x4*)(Wt + tid * 8 + 4);
    bf16x8 yv;
#pragma unroll
    for (int e = 0; e < 4; ++e) {
        yv[e]     = (bf16_t)(xf[e] * scale * w0[e]);
        yv[e + 4] = (bf16_t)(xf[e + 4] * scale * w1[e]);
    }
    *(bf16x8*)(Y + row * 2048 + tid * 8) = yv;
}

// ---------------------------------------------------------------------------
// FAST PATH GEMM (pure bf16, global_load_lds staging, m97 structure).
// Still used for K/V projections (N=1024: grid 8x32 = 256 blocks @ 2/CU).
// ---------------------------------------------------------------------------
__global__ __launch_bounds__(256, 2)
void gemm_bb(const bf16_t* __restrict__ A, const bf16_t* __restrict__ W,
             const float* __restrict__ Rf, const bf16_t* __restrict__ Rb,
             bf16_t* __restrict__ Cb, float* __restrict__ Cf,
             int M, int N, int K, int mode)
{
    __shared__ bf16_t As[128 * 64];
    __shared__ bf16_t Ws[128 * 64];

    const int tid  = threadIdx.x;
    const int lane = tid & 63, wave = tid >> 6;
    const int quad = lane >> 4, l16 = lane & 15;
    const int m0 = blockIdx.y * 128, n0 = blockIdx.x * 128;
    const int wm = (wave >> 1) * 64, wn = (wave & 1) * 64;

    const bf16_t* Ab = A + (size_t)(m0 + (tid >> 3)) * K + ((tid & 7) << 3);
    const bf16_t* Wb = W + (size_t)(n0 + (tid >> 3)) * K + ((tid & 7) << 3);

    f32x4 acc[4][4] = {};

    for (int k0 = 0; k0 < K; k0 += 64) {
        __syncthreads();
#pragma unroll
        for (int i = 0; i < 4; ++i) {
            load_lds16(Ab + (size_t)(i * 32) * K + k0, As + (i * 256 + tid) * 8);
            load_lds16(Wb + (size_t)(i * 32) * K + k0, Ws + (i * 256 + tid) * 8);
        }
        __syncthreads();

#pragma unroll
        for (int ks = 0; ks < 64; ks += 32) {
            bf16x8 af[4], bfr[4];
#pragma unroll
            for (int i = 0; i < 4; ++i)
                af[i] = *(const bf16x8*)(As + (wm + i * 16 + l16) * 64 + ks + quad * 8);
#pragma unroll
            for (int j = 0; j < 4; ++j)
                bfr[j] = *(const bf16x8*)(Ws + (wn + j * 16 + l16) * 64 + ks + quad * 8);
#pragma unroll
            for (int i = 0; i < 4; ++i)
#pragma unroll
                for (int j = 0; j < 4; ++j)
                    acc[i][j] = MFMA16(af[i], bfr[j], acc[i][j]);
        }
    }

#pragma unroll
    for (int i = 0; i < 4; ++i)
#pragma unroll
        for (int j = 0; j < 4; ++j)
#pragma unroll
            for (int r = 0; r < 4; ++r) {
                size_t row = (size_t)(m0 + wm + i * 16 + quad * 4 + r);
                size_t col = (size_t)(n0 + wn + j * 16 + l16);
                float v = acc[i][j][r];
                if (mode == 1) v += Rf[row * (size_t)N + col];
                if (mode == 2)
                    Cf[row * (size_t)N + col] = v + (float)Rb[row * (size_t)N + col];
                else
                    Cb[row * (size_t)N + col] = (bf16_t)v;
            }
}

// ---------------------------------------------------------------------------
// 8-phase GEMM (T1+T2+T3+T4+T5), tile 256x128, 8 waves as 4M x 2N
// (per-wave 64x64), double-buffered 96 KiB LDS, balanced 2 phases/K-tile
// (8 ds_reads -> 16 MFMA each), stage pairs at top/P0/P1, counted vmcnt(2).
// Grid MUST be (M/256)*(N/128) = 256 blocks (M=4096, N=2048).
// mode 0: Cb = acc | 1: Cb = acc + Rf(fp32) | 2: Cf = acc + Rb(bf16)
// ---------------------------------------------------------------------------
__global__ __launch_bounds__(512, 2)
void gemm8(const bf16_t* __restrict__ A, const bf16_t* __restrict__ W,
           const float* __restrict__ Rf, const bf16_t* __restrict__ Rb,
           bf16_t* __restrict__ Cb, float* __restrict__ Cf,
           int M, int N, int K, int mode)
{
    __shared__ bf16_t As[2][256 * 64];   // 64 KiB
    __shared__ bf16_t Ws[2][128 * 64];   // 32 KiB

    const int tid  = threadIdx.x;
    const int lane = tid & 63, wave = tid >> 6;
    const int quad = lane >> 4, l16 = lane & 15;
    const int wr = wave >> 1, wc = wave & 1;   // 4M x 2N wave grid

    // T1: bijective XCD swizzle, A-panel-resident: each XCD owns 2 M-panels
    // (2 x 256 rows; 2 MB of A at K=2048 -> L2-resident) x all 16 N-panels.
    const int lid = (int)blockIdx.x;
    const int swz = (lid & 7) * 32 + (lid >> 3);   // 256 blocks, 704%8==0 n/a
    const int bym = swz >> 4;                      // 0..15
    const int bxn = swz & 15;                      // 0..15
    const int m0 = bym * 256, n0 = bxn * 128;

    const bf16_t* Ab = A + (size_t)m0 * K;
    const bf16_t* Wb = W + (size_t)n0 * K;

    const int xsw  = (l16 & 7) << 3;               // T2 read-side XOR (elems)
    const int aoff = (wr * 64 + l16) * 64;
    const int boff = (wc * 64 + l16) * 64;

    f32x4 acc[4][4] = {};

    // prologue: stage tile 0 fully (6 loads/thread)
    lds_stage2(Ab, As[0], 0,    tid, K, 0);
    lds_stage2(Ab, As[0], 1024, tid, K, 0);
    lds_stage2(Wb, Ws[0], 0,    tid, K, 0);

    const int NT = K >> 6;
    for (int t = 0; t < NT; ++t) {
        const int b  = t & 1;
        const int kn = (t + 1) << 6;
        const bool pf = (t + 1 < NT);
        bf16_t* An = As[1 - b];
        bf16_t* Wn = Ws[1 - b];

        if (pf) {
            lds_stage2(Ab, An, 0, tid, K, kn);
            // T4: drain tile t's 6 loads; the 2 just issued stay in flight.
            asm volatile("s_waitcnt vmcnt(2)" ::: "memory");
        } else {
            asm volatile("s_waitcnt vmcnt(0)" ::: "memory");
        }
        __builtin_amdgcn_s_barrier();   // tile t visible to ALL waves

        const bf16_t* Asb = As[b];
        const bf16_t* Wsb = Ws[b];

#pragma unroll
        for (int ks = 0; ks < 2; ++ks) {
            const int kxo = (ks * 32 + quad * 8) ^ xsw;
            bf16x8 af[4], bf_[4];
#pragma unroll
            for (int i = 0; i < 4; ++i)
                af[i] = *(const bf16x8*)(Asb + aoff + i * 1024 + kxo);
#pragma unroll
            for (int j = 0; j < 4; ++j)
                bf_[j] = *(const bf16x8*)(Wsb + boff + j * 1024 + kxo);
            if (pf) {
                if (ks == 0) lds_stage2(Ab, An, 1024, tid, K, kn);
                else         lds_stage2(Wb, Wn, 0,    tid, K, kn);
            }
            __builtin_amdgcn_s_barrier();
            __builtin_amdgcn_s_setprio(1);
#pragma unroll
            for (int i = 0; i < 4; ++i)
#pragma unroll
                for (int j = 0; j < 4; ++j)
                    acc[i][j] = MFMA16(af[i], bf_[j], acc[i][j]);
            __builtin_amdgcn_s_setprio(0);
            __builtin_amdgcn_s_barrier();
        }
    }

#pragma unroll
    for (int i = 0; i < 4; ++i)
#pragma unroll
        for (int j = 0; j < 4; ++j)
#pragma unroll
            for (int r = 0; r < 4; ++r) {
                size_t row = (size_t)(m0 + wr * 64 + i * 16 + quad * 4 + r);
                size_t col = (size_t)(n0 + wc * 64 + j * 16 + l16);
                float v = acc[i][j][r];
                if (mode == 1) v += Rf[row * (size_t)N + col];
                if (mode == 2)
                    Cf[row * (size_t)N + col] = v + (float)Rb[row * (size_t)N + col];
                else
                    Cb[row * (size_t)N + col] = (bf16_t)v;
            }
}

// ---------------------------------------------------------------------------
// Fused gate+up SwiGLU GEMM, 8-phase rebalanced: tile 256x128, 8 waves 2Mx4N,
// 4 phases/K-tile with reads 8/4/8/4 -> 16 MFMA each, stage pairs at
// top/P0/P1/P2, counted vmcnt(2), setprio, 128 KiB double-buffered LDS.
// C[M,N] = silu(A@G^T) * (A@U^T). Grid 704 blocks of 512 threads.
// ---------------------------------------------------------------------------
__global__ __launch_bounds__(512, 2)
void gateup8(const bf16_t* __restrict__ A, const bf16_t* __restrict__ G,
             const bf16_t* __restrict__ U, bf16_t* __restrict__ C,
             int M, int N, int K)
{
    __shared__ bf16_t As[2][256 * 64];   // 64 KiB
    __shared__ bf16_t Gs[2][128 * 64];   // 32 KiB
    __shared__ bf16_t Us[2][128 * 64];   // 32 KiB

    const int tid  = threadIdx.x;
    const int lane = tid & 63;
    const int wave = tid >> 6;
    const int quad = lane >> 4, l16 = lane & 15;
    const int wr = wave >> 2, wc = wave & 3;      // 2M x 4N wave grid

    // T1: bijective XCD swizzle (704 % 8 == 0).
    const int lid = (int)blockIdx.x;
    const int nwg = (M >> 8) * (N >> 7);          // 16 * 44 = 704
    const int cpx = nwg >> 3;                     // 88
    const int swz = (lid & 7) * cpx + (lid >> 3);
    const int bxn = swz >> 4;                     // N-block (44)
    const int bym = swz & 15;                     // M-block (16)
    const int m0 = bym * 256, n0 = bxn * 128;

    const bf16_t* Ab = A + (size_t)m0 * K;
    const bf16_t* Gb = G + (size_t)n0 * K;
    const bf16_t* Ub = U + (size_t)n0 * K;

    const int xsw  = (l16 & 7) << 3;              // T2 read-side XOR (elems)
    const int aoff = (wr * 128 + l16) * 64;
    const int boff = (wc * 32 + l16) * 64;

    f32x4 accg[8][2] = {};
    f32x4 accu[8][2] = {};

    // prologue: stage tile 0 fully (8 loads/thread)
    lds_stage2(Ab, As[0], 0,    tid, K, 0);
    lds_stage2(Ab, As[0], 1024, tid, K, 0);
    lds_stage2(Gb, Gs[0], 0,    tid, K, 0);
    lds_stage2(Ub, Us[0], 0,    tid, K, 0);

    const int NT = K >> 6;                        // 32 K-tiles
    for (int t = 0; t < NT; ++t) {
        const int b  = t & 1;
        const int kn = (t + 1) << 6;
        const bool pf = (t + 1 < NT);
        bf16_t* An = As[1 - b];
        bf16_t* Gn = Gs[1 - b];
        bf16_t* Un = Us[1 - b];

        if (pf) {
            lds_stage2(Ab, An, 0, tid, K, kn);
            asm volatile("s_waitcnt vmcnt(2)" ::: "memory");
        } else {
            asm volatile("s_waitcnt vmcnt(0)" ::: "memory");
        }
        __builtin_amdgcn_s_barrier();   // tile t visible to ALL waves

        const bf16_t* Asb = As[b];
        const bf16_t* Gsb = Gs[b];
        const bf16_t* Usb = Us[b];

        bf16x8 af[4], bg[2], bu[2];

        // ---- P0: ks=0, A rows lo (8 reads -> 16 MFMA) ----
        {
            const int kxo = (quad * 8) ^ xsw;
#pragma unroll
            for (int i = 0; i < 4; ++i)
                af[i] = *(const bf16x8*)(Asb + aoff + i * 1024 + kxo);
#pragma unroll
            for (int j = 0; j < 2; ++j) {
                bg[j] = *(const bf16x8*)(Gsb + boff + j * 1024 + kxo);
                bu[j] = *(const bf16x8*)(Usb + boff + j * 1024 + kxo);
            }
        }
        if (pf) lds_stage2(Ab, An, 1024, tid, K, kn);
        __builtin_amdgcn_s_barrier();
        __builtin_amdgcn_s_setprio(1);
#pragma unroll
        for (int i = 0; i < 4; ++i)
#pragma unroll
            for (int j = 0; j < 2; ++j) {
                accg[i][j] = MFMA16(af[i], bg[j], accg[i][j]);
                accu[i][j] = MFMA16(af[i], bu[j], accu[i][j]);
            }
        __builtin_amdgcn_s_setprio(0);
        __builtin_amdgcn_s_barrier();

        // ---- P1: ks=0, A rows hi (4 reads -> 16 MFMA) ----
        {
            const int kxo = (quad * 8) ^ xsw;
#pragma unroll
            for (int i = 0; i < 4; ++i)
                af[i] = *(const bf16x8*)(Asb + aoff + (i + 4) * 1024 + kxo);
        }
        if (pf) lds_stage2(Gb, Gn, 0, tid, K, kn);
        __builtin_amdgcn_s_barrier();
        __builtin_amdgcn_s_setprio(1);
#pragma unroll
        for (int i = 0; i < 4; ++i)
#pragma unroll
            for (int j = 0; j < 2; ++j) {
                accg[i + 4][j] = MFMA16(af[i], bg[j], accg[i + 4][j]);
                accu[i + 4][j] = MFMA16(af[i], bu[j], accu[i + 4][j]);
            }
        __builtin_amdgcn_s_setprio(0);
        __builtin_amdgcn_s_barrier();

        // ---- P2: ks=1, A rows lo (8 reads -> 16 MFMA) ----
        {
            const int kxo = (32 + quad * 8) ^ xsw;
#pragma unroll
            for (int i = 0; i < 4; ++i)
                af[i] = *(const bf16x8*)(Asb + aoff + i * 1024 + kxo);
#pragma unroll
            for (int j = 0; j < 2; ++j) {
                bg[j] = *(const bf16x8*)(Gsb + boff + j * 1024 + kxo);
                bu[j] = *(const bf16x8*)(Usb + boff + j * 1024 + kxo);
            }
        }
        if (pf) lds_stage2(Ub, Un, 0, tid, K, kn);
        __builtin_amdgcn_s_barrier();
        __builtin_amdgcn_s_setprio(1);
#pragma unroll
        for (int i = 0; i < 4; ++i)
#pragma unroll
            for (int j = 0; j < 2; ++j) {
                accg[i][j] = MFMA16(af[i], bg[j], accg[i][j]);
                accu[i][j] = MFMA16(af[i], bu[j], accu[i][j]);
            }
        __builtin_amdgcn_s_setprio(0);
        __builtin_amdgcn_s_barrier();

        // ---- P3: ks=1, A rows hi (4 reads -> 16 MFMA) ----
        {
            const int kxo = (32 + quad * 8) ^ xsw;
#pragma unroll
            for (int i = 0; i < 4; ++i)
                af[i] = *(const bf16x8*)(Asb + aoff + (i + 4) * 1024 + kxo);
        }
        __builtin_amdgcn_s_barrier();
        __builtin_amdgcn_s_setprio(1);
#pragma unroll
        for (int i = 0; i < 4; ++i)
#pragma unroll
            for (int j = 0; j < 2; ++j) {
                accg[i + 4][j] = MFMA16(af[i], bg[j], accg[i + 4][j]);
                accu[i + 4][j] = MFMA16(af[i], bu[j], accu[i + 4][j]);
            }
        __builtin_amdgcn_s_setprio(0);
        __builtin_amdgcn_s_barrier();   // end-of-tile: all reads of buf b done
    }

    // epilogue: silu(g) * u
#pragma unroll
    for (int i = 0; i < 8; ++i)
#pragma unroll
        for (int j = 0; j < 2; ++j)
#pragma unroll
            for (int r = 0; r < 4; ++r) {
                size_t row = (size_t)(m0 + wr * 128 + i * 16 + quad * 4 + r);
                size_t col = (size_t)(n0 + wc * 32 + j * 16 + l16);
                float g = accg[i][j][r];
                float u = accu[i][j][r];
                float sig = 1.f / (1.f + __expf(fminf(-g, 80.f)));
                C[row * (size_t)N + col] = (bf16_t)(g * sig * u);
            }
}

// ---------------------------------------------------------------------------
// FALLBACK GEMM (round-4 path, fp32 weights staged in registers)
// ---------------------------------------------------------------------------
__global__ __launch_bounds__(256, 2)
void gemm_bt(const bf16_t* __restrict__ A, const float* __restrict__ W,
             const float* __restrict__ Rf, const bf16_t* __restrict__ Rb,
             bf16_t* __restrict__ Cb, float* __restrict__ Cf,
             int M, int N, int K, int mode)
{
    __shared__ bf16_t As[128 * 64];
    __shared__ bf16_t Ws[128 * 64];

    const int tid  = threadIdx.x;
    const int lane = tid & 63, wave = tid >> 6;
    const int quad = lane >> 4, l16 = lane & 15;
    const int m0 = blockIdx.y * 128, n0 = blockIdx.x * 128;
    const int wm = (wave >> 1) * 64, wn = (wave & 1) * 64;

    f32x4 acc[4][4] = {};

    for (int k0 = 0; k0 < K; k0 += 64) {
        bf16x8 ra[4];
        bf16x4 rw[8];
#pragma unroll
        for (int i = 0; i < 4; ++i) {
            int u = i * 256 + tid;
            int r = u >> 3, c = (u & 7) << 3;
            ra[i] = *(const bf16x8*)(A + (size_t)(m0 + r) * K + k0 + c);
        }
#pragma unroll
        for (int i = 0; i < 8; ++i) {
            int u = i * 256 + tid;
            int r = u >> 4, c = (u & 15) << 2;
            f32x4 w4 = *(const f32x4*)(W + (size_t)(n0 + r) * K + k0 + c);
#pragma unroll
            for (int e = 0; e < 4; ++e) rw[i][e] = (bf16_t)w4[e];
        }
        __syncthreads();
#pragma unroll
        for (int i = 0; i < 4; ++i)
            *(bf16x8*)(As + (i * 256 + tid) * 8) = ra[i];
#pragma unroll
        for (int i = 0; i < 8; ++i)
            *(bf16x4*)(Ws + (i * 256 + tid) * 4) = rw[i];
        __syncthreads();

#pragma unroll
        for (int ks = 0; ks < 64; ks += 32) {
            bf16x8 af[4], bfr[4];
#pragma unroll
            for (int i = 0; i < 4; ++i)
                af[i] = *(const bf16x8*)(As + (wm + i * 16 + l16) * 64 + ks + quad * 8);
#pragma unroll
            for (int j = 0; j < 4; ++j)
                bfr[j] = *(const bf16x8*)(Ws + (wn + j * 16 + l16) * 64 + ks + quad * 8);
#pragma unroll
            for (int i = 0; i < 4; ++i)
#pragma unroll
                for (int j = 0; j < 4; ++j)
                    acc[i][j] = MFMA16(af[i], bfr[j], acc[i][j]);
        }
    }

#pragma unroll
    for (int i = 0; i < 4; ++i)
#pragma unroll
        for (int j = 0; j < 4; ++j)
#pragma unroll
            for (int r = 0; r < 4; ++r) {
                size_t row = (size_t)(m0 + wm + i * 16 + quad * 4 + r);
                size_t col = (size_t)(n0 + wn + j * 16 + l16);
                float v = acc[i][j][r];
                if (mode == 1) v += Rf[row * (size_t)N + col];
                if (mode == 2)
                    Cf[row * (size_t)N + col] = v + (float)Rb[row * (size_t)N + col];
                else
                    Cb[row * (size_t)N + col] = (bf16_t)v;
            }
}

// ---------------------------------------------------------------------------
// FALLBACK fused gate+up (round-4 path, fp32 weights)
// ---------------------------------------------------------------------------
__global__ __launch_bounds__(256, 2)
void gemm_gateup(const bf16_t* __restrict__ A, const float* __restrict__ G,
                 const float* __restrict__ U, bf16_t* __restrict__ C,
                 int M, int N, int K)
{
    __shared__ bf16_t As[128 * 64];
    __shared__ bf16_t Gs[128 * 64];
    __shared__ bf16_t Us[128 * 64];

    const int tid  = threadIdx.x;
    const int lane = tid & 63, wave = tid >> 6;
    const int quad = lane >> 4, l16 = lane & 15;
    const int m0 = blockIdx.y * 128, n0 = blockIdx.x * 128;
    const int wm = (wave >> 1) * 64, wn = (wave & 1) * 64;

    f32x4 accg[4][4] = {};
    f32x4 accu[4][4] = {};

    for (int k0 = 0; k0 < K; k0 += 64) {
        bf16x8 ra[4];
        bf16x4 rg[8], ru[8];
#pragma unroll
        for (int i = 0; i < 4; ++i) {
            int u = i * 256 + tid;
            int r = u >> 3, c = (u & 7) << 3;
            ra[i] = *(const bf16x8*)(A + (size_t)(m0 + r) * K + k0 + c);
        }
#pragma unroll
        for (int i = 0; i < 8; ++i) {
            int u = i * 256 + tid;
            int r = u >> 4, c = (u & 15) << 2;
            f32x4 g4 = *(const f32x4*)(G + (size_t)(n0 + r) * K + k0 + c);
            f32x4 u4 = *(const f32x4*)(U + (size_t)(n0 + r) * K + k0 + c);
#pragma unroll
            for (int e = 0; e < 4; ++e) { rg[i][e] = (bf16_t)g4[e]; ru[i][e] = (bf16_t)u4[e]; }
        }
        __syncthreads();
#pragma unroll
        for (int i = 0; i < 4; ++i)
            *(bf16x8*)(As + (i * 256 + tid) * 8) = ra[i];
#pragma unroll
        for (int i = 0; i < 8; ++i) {
            *(bf16x4*)(Gs + (i * 256 + tid) * 4) = rg[i];
            *(bf16x4*)(Us + (i * 256 + tid) * 4) = ru[i];
        }
        __syncthreads();

#pragma unroll
        for (int ks = 0; ks < 64; ks += 32) {
            bf16x8 af[4], bg[4], bu[4];
#pragma unroll
            for (int i = 0; i < 4; ++i)
                af[i] = *(const bf16x8*)(As + (wm + i * 16 + l16) * 64 + ks + quad * 8);
#pragma unroll
            for (int j = 0; j < 4; ++j) {
                bg[j] = *(const bf16x8*)(Gs + (wn + j * 16 + l16) * 64 + ks + quad * 8);
                bu[j] = *(const bf16x8*)(Us + (wn + j * 16 + l16) * 64 + ks + quad * 8);
            }
#pragma unroll
            for (int i = 0; i < 4; ++i)
#pragma unroll
                for (int j = 0; j < 4; ++j) {
                    accg[i][j] = MFMA16(af[i], bg[j], accg[i][j]);
                    accu[i][j] = MFMA16(af[i], bu[j], accu[i][j]);
                }
        }
    }

#pragma unroll
    for (int i = 0; i < 4; ++i)
#pragma unroll
        for (int j = 0; j < 4; ++j)
#pragma unroll
            for (int r = 0; r < 4; ++r) {
                size_t row = (size_t)(m0 + wm + i * 16 + quad * 4 + r);
                size_t col = (size_t)(n0 + wn + j * 16 + l16);
                float g = accg[i][j][r];
                float u = accu[i][j][r];
                float sig = 1.f / (1.f + __expf(fminf(-g, 80.f)));
                C[row * (size_t)N + col] = (bf16_t)(g * sig * u);
            }
}

// ---------------------------------------------------------------------------
// Flash attention fwd (round-4 version: swizzled Vt, padded Pl, paired q-tiles)
// ---------------------------------------------------------------------------
__global__ __launch_bounds__(256, 2)
void attn_fwd(const bf16_t* __restrict__ Q, const bf16_t* __restrict__ Kg,
              const bf16_t* __restrict__ Vg, bf16_t* __restrict__ O)
{
    __shared__ bf16_t Ks[64 * 128];
    __shared__ bf16_t Vt[128 * 64];      // Vt[d][k], k-blocks XOR-swizzled by d&7
    __shared__ bf16_t Pl[4][16 * 72];    // padded stride 72

    const int tid  = threadIdx.x;
    const int lane = tid & 63, wave = tid >> 6;
    const int quad = lane >> 4, l16 = lane & 15;
    const int bh = blockIdx.y, b = bh >> 4, h = bh & 15;

    const bf16_t* Qh = Q  + (size_t)b * 2048 * 2048 + (size_t)h * 128;
    const bf16_t* Kh = Kg + (size_t)b * 2048 * 1024 + (size_t)(h >> 1) * 128;
    const bf16_t* Vh = Vg + (size_t)b * 2048 * 1024 + (size_t)(h >> 1) * 128;

    const float scale = 0.08838834764831845f;   // 1/sqrt(128)

#pragma unroll 1
    for (int pass = 0; pass < 2; ++pass) {
        const int qt = pass ? (31 - (int)blockIdx.x) : (int)blockIdx.x;
        const int q0 = qt * 64;

        bf16x8 aq[4];
#pragma unroll
        for (int ks = 0; ks < 4; ++ks)
            aq[ks] = *(const bf16x8*)(Qh + (size_t)(q0 + wave * 16 + l16) * 2048 + ks * 32 + quad * 8);

        float m_r[4] = { -30000.f, -30000.f, -30000.f, -30000.f };
        float l_r[4] = { 0.f, 0.f, 0.f, 0.f };
        f32x4 acc_o[8] = {};

        const int ntiles = qt + 1;

        for (int t = 0; t < ntiles; ++t) {
            const int kv0 = t * 64;
            __syncthreads();
#pragma unroll
            for (int i = 0; i < 4; ++i) {
                int u = i * 256 + tid;
                int rk = u >> 4, c = (u & 15) << 3;
                *(bf16x8*)(Ks + u * 8) =
                    *(const bf16x8*)(Kh + (size_t)(kv0 + rk) * 1024 + c);
            }
#pragma unroll
            for (int it = 0; it < 4; ++it) {
                int v = it * 256 + tid;
                int d = v & 127, kb = v >> 7;
                bf16x8 vt8;
#pragma unroll
                for (int j = 0; j < 8; ++j)
                    vt8[j] = Vh[(size_t)(kv0 + kb * 8 + j) * 1024 + d];
                *(bf16x8*)(Vt + d * 64 + ((kb ^ (d & 7)) << 3)) = vt8;
            }
            __syncthreads();

            f32x4 accs[4] = {};
#pragma unroll
            for (int ks = 0; ks < 4; ++ks)
#pragma unroll
                for (int j = 0; j < 4; ++j) {
                    bf16x8 bk = *(const bf16x8*)(Ks + (j * 16 + l16) * 128 + ks * 32 + quad * 8);
                    accs[j] = MFMA16(aq[ks], bk, accs[j]);
                }

#pragma unroll
            for (int r = 0; r < 4; ++r) {
                const int qrow = q0 + wave * 16 + quad * 4 + r;
                float s[4];
                float mx = -30000.f;
#pragma unroll
                for (int j = 0; j < 4; ++j) {
                    s[j] = accs[j][r] * scale;
                    if (kv0 + j * 16 + l16 > qrow) s[j] = -30000.f;
                    mx = fmaxf(mx, s[j]);
                }
                mx = fmaxf(mx, __shfl_xor(mx, 1, 64));
                mx = fmaxf(mx, __shfl_xor(mx, 2, 64));
                mx = fmaxf(mx, __shfl_xor(mx, 4, 64));
                mx = fmaxf(mx, __shfl_xor(mx, 8, 64));
                float mnew  = fmaxf(m_r[r], mx);
                float alpha = __expf(fmaxf(m_r[r] - mnew, -80.f));
                float rs = 0.f;
#pragma unroll
                for (int j = 0; j < 4; ++j) {
                    float p = __expf(fmaxf(s[j] - mnew, -80.f));
                    rs += p;
                    Pl[wave][(quad * 4 + r) * 72 + j * 16 + l16] = (bf16_t)p;
                }
                rs += __shfl_xor(rs, 1, 64);
                rs += __shfl_xor(rs, 2, 64);
                rs += __shfl_xor(rs, 4, 64);
                rs += __shfl_xor(rs, 8, 64);
                l_r[r] = l_r[r] * alpha + rs;
                m_r[r] = mnew;
#pragma unroll
                for (int nt = 0; nt < 8; ++nt) acc_o[nt][r] *= alpha;
            }

            __syncthreads();

#pragma unroll
            for (int ks2 = 0; ks2 < 2; ++ks2) {
                bf16x8 ap = *(const bf16x8*)(&Pl[wave][l16 * 72 + ks2 * 32 + quad * 8]);
                const int kb_r = ks2 * 4 + quad;
#pragma unroll
                for (int nt = 0; nt < 8; ++nt) {
                    const int d = nt * 16 + l16;
                    bf16x8 bv = *(const bf16x8*)(Vt + d * 64 + ((kb_r ^ (d & 7)) << 3));
                    acc_o[nt] = MFMA16(ap, bv, acc_o[nt]);
                }
            }
        }

#pragma unroll
        for (int r = 0; r < 4; ++r) {
            float inv = 1.f / fmaxf(l_r[r], 1e-30f);
            size_t orow = (size_t)b * 2048 + q0 + wave * 16 + quad * 4 + r;
#pragma unroll
            for (int nt = 0; nt < 8; ++nt)
                O[orow * 2048 + h * 128 + nt * 16 + l16] = (bf16_t)(acc_o[nt][r] * inv);
        }
    }
}

// ---------------------------------------------------------------------------
// Launch. Fast path (ws >= 174 MB): pre-convert weights to bf16 once, then
// pure-bf16 GEMMs. Q/O/down use the 8-phase gemm8 (grid 256, one round);
// K/V use gemm_bb; MLP gate+up uses the rebalanced gateup8.
// Branch is on ws_size (constant across calls) -> graph-capture safe.
// ---------------------------------------------------------------------------
extern "C" void kernel_launch(void* const* d_in, const int* in_sizes, int n_in,
                              void* d_out, int out_size, void* d_ws, size_t ws_size,
                              hipStream_t stream)
{
    const float* x   = (const float*)d_in[0];
    const float* qw  = (const float*)d_in[2];
    const float* kw  = (const float*)d_in[3];
    const float* vw  = (const float*)d_in[4];
    const float* ow  = (const float*)d_in[5];
    const float* gw  = (const float*)d_in[6];
    const float* uw  = (const float*)d_in[7];
    const float* dw  = (const float*)d_in[8];
    const float* ln1 = (const float*)d_in[9];
    const float* ln2 = (const float*)d_in[10];
    float*  out = (float*)d_out;
    bf16_t* ws  = (bf16_t*)d_ws;

    dim3 blk(256);
    const size_t NEED = 87031808ull * 2;   // 174 MB

    if (ws_size >= NEED) {
        // ---- fast path: bf16 weights + async-staged GEMMs ----
        bf16_t* wq = ws;                      // 4,194,304
        bf16_t* wk = ws + 4194304;            // 2,097,152
        bf16_t* wv = ws + 6291456;            // 2,097,152
        bf16_t* wo = ws + 8388608;            // 4,194,304
        bf16_t* wg = ws + 12582912;           // 11,534,336
        bf16_t* wu = ws + 24117248;           // 11,534,336
        bf16_t* wd = ws + 35651584;           // 11,534,336
        bf16_t* h1 = ws + 47185920;           // 8,388,608
        bf16_t* qb = ws + 55574528;           // 8,388,608 (later hb)
        bf16_t* kb = ws + 63963136;           // 4,194,304 (later gb)
        bf16_t* vb = ws + 68157440;           // 4,194,304
        bf16_t* ab = (bf16_t*)d_out;          // attn out scratch in d_out
        bf16_t* hb = qb;
        bf16_t* gb = kb;                      // 23,068,672 ends at 87,031,808

        wconv<<<2048, blk, 0, stream>>>(qw, wq, 4194304);
        wconv<<<1024, blk, 0, stream>>>(kw, wk, 2097152);
        wconv<<<1024, blk, 0, stream>>>(vw, wv, 2097152);
        wconv<<<2048, blk, 0, stream>>>(ow, wo, 4194304);
        wconv<<<5632, blk, 0, stream>>>(gw, wg, 11534336);
        wconv<<<5632, blk, 0, stream>>>(uw, wu, 11534336);
        wconv<<<5632, blk, 0, stream>>>(dw, wd, 11534336);

        rmsnorm_f32<<<4096, blk, 0, stream>>>(x, ln1, h1);
        gemm8<<<256, dim3(512), 0, stream>>>(h1, wq, nullptr, nullptr, qb, nullptr, 4096, 2048, 2048, 0);
        gemm_bb<<<dim3( 8, 32), blk, 0, stream>>>(h1, wk, nullptr, nullptr, kb, nullptr, 4096, 1024, 2048, 0);
        gemm_bb<<<dim3( 8, 32), blk, 0, stream>>>(h1, wv, nullptr, nullptr, vb, nullptr, 4096, 1024, 2048, 0);
        attn_fwd<<<dim3(16, 32), blk, 0, stream>>>(qb, kb, vb, ab);
        gemm8<<<256, dim3(512), 0, stream>>>(ab, wo, x, nullptr, hb, nullptr, 4096, 2048, 2048, 1);
        rmsnorm_bf16<<<4096, blk, 0, stream>>>(hb, ln2, h1);
        gateup8<<<704, dim3(512), 0, stream>>>(h1, wg, wu, gb, 4096, 5632, 2048);
        gemm8<<<256, dim3(512), 0, stream>>>(gb, wd, nullptr, hb, nullptr, out, 4096, 2048, 5632, 2);
    } else {
        // ---- fallback: round-4 mixed path (78 MB) ----
        const size_t ME = 1ull << 20;
        bf16_t* h1 = ws;
        bf16_t* qb = ws + 8  * ME;
        bf16_t* kb = ws + 16 * ME;
        bf16_t* vb = ws + 20 * ME;
        bf16_t* ab = (bf16_t*)d_out;
        bf16_t* hb = ws + 8  * ME;
        bf16_t* gb = ws + 16 * ME;

        rmsnorm_f32<<<4096, blk, 0, stream>>>(x, ln1, h1);
        gemm_bt<<<dim3(16, 32), blk, 0, stream>>>(h1, qw, nullptr, nullptr, qb, nullptr, 4096, 2048, 2048, 0);
        gemm_bt<<<dim3( 8, 32), blk, 0, stream>>>(h1, kw, nullptr, nullptr, kb, nullptr, 4096, 1024, 2048, 0);
        gemm_bt<<<dim3( 8, 32), blk, 0, stream>>>(h1, vw, nullptr, nullptr, vb, nullptr, 4096, 1024, 2048, 0);
        attn_fwd<<<dim3(16, 32), blk, 0, stream>>>(qb, kb, vb, ab);
        gemm_bt<<<dim3(16, 32), blk, 0, stream>>>(ab, ow, x, nullptr, hb, nullptr, 4096, 2048, 2048, 1);
        rmsnorm_bf16<<<4096, blk, 0, stream>>>(hb, ln2, h1);
        gemm_gateup<<<dim3(44, 32), blk, 0, stream>>>(h1, gw, uw, gb, 4096, 5632, 2048);
        gemm_bt<<<dim3(16, 32), blk, 0, stream>>>(gb, dw, nullptr, hb, nullptr, out, 4096, 2048, 5632, 2);
    }
}